// Round 12
// baseline (637.201 us; speedup 1.0000x reference)
//
#include <hip/hip_runtime.h>
#include <math.h>

constexpr int NN = 4000;
constexpr int EE = 48000;
constexpr int ZZ = 10;
constexpr float RMAX = 5.0f;
constexpr float INV_AVG = 1.0f / 12.0f;

constexpr int GRID  = 512;            // 2 blocks/CU x 256 CU -> all co-resident
constexpr int NWAVE = GRID * 4;       // 2048 waves

// P1 role layout
constexpr int RB_EDGE = 188;          // [0,188)   edges
constexpr int RB_SPEC = 204;          // [188,204) species
constexpr int RB_W3Z  = 236;          // [204,236) Wm3 l=0 gather
constexpr int RB_T0   = 239;          // [236,239) per-species tables
// [239,512) zero role
constexpr int ZWS_F4  = 3*NN*64/4;    // agg0,agg1,ghb at ws base
constexpr int ZOUT_F4 = 3*NN/4;       // out force region

#define MAIN_KERNEL __global__ __launch_bounds__(256) __attribute__((amdgpu_waves_per_eu(2,2)))

__device__ __forceinline__ float rl(float v, int lane){
    return __uint_as_float(__builtin_amdgcn_readlane(__float_as_uint(v), lane));
}
__device__ __forceinline__ int rfl(int v){ return __builtin_amdgcn_readfirstlane(v); }
__device__ __forceinline__ float sigf(float x){ return 1.0f/(1.0f+__expf(-x)); }
__device__ __forceinline__ float siluf(float x){ return x*sigf(x); }
__device__ __forceinline__ float dsiluf(float x){ float s=sigf(x); return s*(1.0f+x*(1.0f-s)); }

__device__ __forceinline__ void pin64(float (&W)[64]){
#pragma unroll
    for (int i=0;i<64;i++) asm volatile("" : "+v"(W[i]));
}
__device__ __forceinline__ void pin8(float (&W)[8]){
#pragma unroll
    for (int i=0;i<8;i++) asm volatile("" : "+v"(W[i]));
}

// wave-uniform activation pointer: s_load + v_fmac(s, v)
__device__ __forceinline__ float bmv_s(const float* act, const float (&W)[64]){
    float a0=0.f,a1=0.f,a2=0.f,a3=0.f;
#pragma unroll
    for (int k=0;k<64;k+=4){
        a0 += act[k+0]*W[k+0];
        a1 += act[k+1]*W[k+1];
        a2 += act[k+2]*W[k+2];
        a3 += act[k+3]*W[k+3];
    }
    return (a0+a1)+(a2+a3);
}
// per-lane value broadcast via per-wave LDS slice
__device__ __forceinline__ float bmv_lds(float v, const float (&W)[64], float* slice, int lane){
    slice[lane] = v;
    float a0=0.f,a1=0.f,a2=0.f,a3=0.f;
#pragma unroll
    for (int k=0;k<64;k+=4){
        float4 a = *reinterpret_cast<const float4*>(slice + k);
        a0 += a.x*W[k+0];
        a1 += a.y*W[k+1];
        a2 += a.z*W[k+2];
        a3 += a.w*W[k+3];
    }
    return (a0+a1)+(a2+a3);
}
__device__ __forceinline__ void load_row64(const float* __restrict__ p, float (&W)[64]){
#pragma unroll
    for (int i=0;i<16;i++){
        float4 v = reinterpret_cast<const float4*>(p)[i];
        W[4*i]=v.x; W[4*i+1]=v.y; W[4*i+2]=v.z; W[4*i+3]=v.w;
    }
}
__device__ __forceinline__ void load_col64(const float* __restrict__ p, int lane, float (&W)[64]){
#pragma unroll
    for (int k=0;k<64;k++) W[k] = p[k*64+lane];
}

// device-wide barrier: per-id dedicated counter, device-scope atomics + fences
__device__ __forceinline__ void gbar(int* __restrict__ bc, int id){
    __syncthreads();
    if (threadIdx.x == 0){
        __threadfence();
        __hip_atomic_fetch_add(bc + id*64, 1, __ATOMIC_RELEASE, __HIP_MEMORY_SCOPE_AGENT);
        while (__hip_atomic_load(bc + id*64, __ATOMIC_ACQUIRE, __HIP_MEMORY_SCOPE_AGENT) < GRID)
            __builtin_amdgcn_s_sleep(1);
        __threadfence();
    }
    __syncthreads();
}

// ---------------- pre-kernel: barrier counters + ecount + snap header ----------------
__global__ void k_zero(int* __restrict__ barcnt, int* __restrict__ ecount, float* __restrict__ out)
{
    int t = threadIdx.x;
    barcnt[t] = 0; barcnt[t+256] = 0;
    if (t == 0) *ecount = 0;
    if (t < 8) out[t] = 0.0f;
}

// ---------------- the whole model: 8 phases, 7 device barriers ----------------
MAIN_KERNEL
void k_main(const float* __restrict__ pos, const float* __restrict__ shifts,
            const int* __restrict__ ei, const float* __restrict__ x,
            const float* __restrict__ WE, const float* __restrict__ W_up,
            const float* __restrict__ Wm1, const float* __restrict__ Wm2,
            const float* __restrict__ Wm3, const float* __restrict__ W_out,
            const float* __restrict__ W_sc, const float* __restrict__ a_sc,
            const float* __restrict__ w_poly, const float* __restrict__ W_prod,
            const float* __restrict__ w_r0, const float* __restrict__ W_r1,
            const float* __restrict__ w_r2, const int* __restrict__ batch,
            int* __restrict__ spec, float* __restrict__ u3c,
            float* __restrict__ frc, float* __restrict__ dfrc,
            int* __restrict__ esrc, int* __restrict__ edst, int* __restrict__ ecount,
            float* __restrict__ T0, float* __restrict__ SC0, float* __restrict__ W3z,
            float* __restrict__ agg0, float* __restrict__ agg1, float* __restrict__ ghb,
            float* __restrict__ t2b0, float* __restrict__ t2b1, float* __restrict__ w0b1,
            float* __restrict__ h1b, float* __restrict__ nf1b, float* __restrict__ s0b,
            float* __restrict__ gagg0, float* __restrict__ gagg1, float* __restrict__ gacc,
            int* __restrict__ barcnt, float4* __restrict__ zws,
            float* __restrict__ out)
{
    __shared__ float part[8];
    __shared__ float sact[4][64];
    const int bid  = blockIdx.x;
    const int tid  = threadIdx.x;
    const int lane = tid & 63;
    float* slice = sact[tid>>6];
    const int gw = rfl(bid*4 + (tid>>6));       // uniform wave id 0..2047

    const float* U0  = W_up;          const float* U1  = W_up   + 16384;
    const float* O0  = W_out;         const float* O1  = W_out  + 16384;
    const float* S0w = W_sc;          const float* S1w = W_sc   + 16384;
    const float* P0w = W_prod;        const float* P1w = W_prod + 16384;
    const float* M1_0= Wm1;           const float* M1_1= Wm1 + 512;
    const float* M2_0= Wm2;           const float* M2_1= Wm2 + 4096;
    const float* asc1= a_sc + ZZ*64;
    const float* pl0 = w_poly;        const float* pl1 = w_poly + 192;
    const float* W3z0= W3z;           const float* W3z1= W3z + 4096;
    float* outf = out + 8 + NN;

    // ================= P1: geometry+compaction / spec / W3z / tables / zero =================
    if (bid < RB_EDGE){
        int e = bid*256 + tid;
        if (e < EE){
            int s = ei[e], r = ei[EE+e];
            float vx = pos[r*3+0]-pos[s*3+0]+shifts[e*3+0];
            float vy = pos[r*3+1]-pos[s*3+1]+shifts[e*3+1];
            float vz = pos[r*3+2]-pos[s*3+2]+shifts[e*3+2];
            float rr = sqrtf(vx*vx+vy*vy+vz*vz);
            float u = rr*(1.0f/RMAX);
            if (u < 1.0f){
                int slot = atomicAdd(ecount, 1);
                esrc[slot]=s; edst[slot]=r;
                float inv = 1.0f/rr;
                u3c[slot*3+0]=vx*inv; u3c[slot*3+1]=vy*inv; u3c[slot*3+2]=vz*inv;
                float u2=u*u, u4=u2*u2, u5=u4*u;
                float env  = 1.0f - 21.0f*u5 + 35.0f*u5*u - 15.0f*u5*u2;
                float om   = 1.0f-u;
                float denv = -21.0f*u4*om*om;
                const float A  = 0.6324555320336759f;
                const float K1 = 3.14159265358979f/RMAX;
                float a  = K1*rr;
                float s1 = __sinf(a), c1 = __cosf(a);
                float sp = 0.0f, cp = 1.0f, sn = s1, cn = c1;
#pragma unroll
                for (int n=1;n<=8;n++){
                    float k = (float)n*K1;
                    float bess  = A*sn*inv;
                    float dbess = A*(k*cn - sn*inv)*inv;
                    frc [slot*8+n-1] = bess*env;
                    dfrc[slot*8+n-1] = dbess*env + bess*denv;
                    float s2 = 2.0f*c1*sn - sp; sp=sn; sn=s2;
                    float c2 = 2.0f*c1*cn - cp; cp=cn; cn=c2;
                }
            }
        }
    } else if (bid < RB_SPEC){
        int n = (bid-RB_EDGE)*256 + tid;
        if (n < NN){
            int sp = 0;
#pragma unroll
            for (int j=0;j<ZZ;j++) if (x[n*ZZ+j] > 0.5f) sp = j;
            spec[n] = sp;
        }
    } else if (bid < RB_W3Z){
        int idx = (bid-RB_SPEC)*256 + tid;      // 0..8191
        int l = idx >> 12, kc = idx & 4095;
        int k = kc >> 6, c = kc & 63;
        W3z[idx] = Wm3[l*64*256 + k*256 + 4*c];
    } else if (bid < RB_T0){
        int wv = (bid-RB_W3Z)*4 + (tid>>6);
        if (wv < ZZ){
            float wev = WE[wv*64 + lane];
            float t=0.f, sc=0.f;
#pragma unroll
            for (int c=0;c<64;c++){
                float w = rl(wev,c);
                t  += w*U0 [c*64+lane];
                sc += w*S0w[c*64+lane];
            }
            T0 [wv*64+lane] = t;
            SC0[wv*64+lane] = sc * a_sc[wv*64+lane];
        }
    } else {
        float4 z4 = make_float4(0.f,0.f,0.f,0.f);
        float4* zout = (float4*)outf;
        for (int i=(bid-RB_T0)*256 + tid; i < ZWS_F4 + ZOUT_F4; i += (GRID-RB_T0)*256){
            if (i < ZWS_F4) zws[i] = z4;
            else zout[i-ZWS_F4] = z4;
        }
    }
    gbar(barcnt, 0);

    // ================= P2: edge MLP fwd layer0 (stash t2b0) =================
    {
        int cnt = ecount[0];
        float W1c[8], W2c[64], W3c[64];
#pragma unroll
        for (int j=0;j<8;j++) W1c[j] = M1_0[j*64+lane];
        load_col64(M2_0, lane, W2c);
        load_col64(W3z0, lane, W3c);
        pin8(W1c); pin64(W2c); pin64(W3c);
        for (int slot=gw; slot<cnt; slot+=NWAVE){
            int us = rfl(slot);
            int s = esrc[us], r = edst[us];
            const float* fn = frc + us*8;          // uniform -> s_load
            float t1=0.f;
#pragma unroll
            for (int j=0;j<8;j++) t1 += fn[j]*W1c[j];
            float t2 = bmv_lds(siluf(t1), W2c, slice, lane);
            t2b0[(size_t)us*64+lane] = t2;
            float w0 = bmv_lds(siluf(t2), W3c, slice, lane);
            float h  = T0[spec[s]*64+lane];
            atomicAdd(&agg0[r*64+lane], w0*h*INV_AVG);
        }
    }
    gbar(barcnt, 1);

    // ================= P3: node fwd layer0 (s0, nf1, h1, node_e, snap) =================
    {
        if (tid < 8) part[tid] = 0.f;
        __syncthreads();
        float WA[64], WB[64], WC[64];
        load_col64(O0,  lane, WA);
        load_col64(P0w, lane, WB);
        load_col64(U1,  lane, WC);
        pin64(WA); pin64(WB); pin64(WC);
        float p0=pl0[lane], p1=pl0[64+lane], p2=pl0[128+lane];
        float w0r = w_r0[lane];
        for (int n=gw; n<NN; n+=NWAVE){
            const float* an = agg0 + n*64;          // uniform -> s_load
            float s  = bmv_s(an, WA);
            float gate = p0 + p1*s + p2*s*s;
            float nf = bmv_lds(s*gate, WB, slice, lane) + SC0[spec[n]*64+lane];
            s0b [n*64+lane] = s;
            nf1b[n*64+lane] = nf;
            h1b [n*64+lane] = bmv_lds(nf, WC, slice, lane);
            float ne = nf*w0r;
#pragma unroll
            for (int off=32;off;off>>=1) ne += __shfl_xor(ne,off);
            if (lane==0){ out[8+n] = ne; atomicAdd(&part[batch[n]], ne); }
        }
        __syncthreads();
        if (tid < 8) atomicAdd(&out[tid], part[tid]);
    }
    gbar(barcnt, 2);

    // ================= P4: edge MLP fwd layer1 (stash t2b1, w0b1) =================
    {
        int cnt = ecount[0];
        float W1c[8], W2c[64], W3c[64];
#pragma unroll
        for (int j=0;j<8;j++) W1c[j] = M1_1[j*64+lane];
        load_col64(M2_1, lane, W2c);
        load_col64(W3z1, lane, W3c);
        pin8(W1c); pin64(W2c); pin64(W3c);
        for (int slot=gw; slot<cnt; slot+=NWAVE){
            int us = rfl(slot);
            int s = esrc[us], r = edst[us];
            const float* fn = frc + us*8;
            float t1=0.f;
#pragma unroll
            for (int j=0;j<8;j++) t1 += fn[j]*W1c[j];
            float t2 = bmv_lds(siluf(t1), W2c, slice, lane);
            t2b1[(size_t)us*64+lane] = t2;
            float w0 = bmv_lds(siluf(t2), W3c, slice, lane);
            w0b1[(size_t)us*64+lane] = w0;
            float h  = h1b[s*64+lane];
            atomicAdd(&agg1[r*64+lane], w0*h*INV_AVG);
        }
    }
    gbar(barcnt, 3);

    // ================= P5: fused node layer1 fwd + readout fwd/bwd + node bwd =================
    {
        if (tid < 8) part[tid] = 0.f;
        __syncthreads();
        int na = gw, nb = gw + NWAVE;
        bool vb = nb < NN;
        int spa = spec[na], spb = vb ? spec[nb] : 0;
        float p0=pl1[lane], p1=pl1[64+lane], p2=pl1[128+lane];
        float sA, sB=0.f, nfA, nfB=0.f, gA, gB=0.f;
        {   // phase a: forward (col-form)
            float WA[64], WB[64], WC[64];
            load_col64(O1,  lane, WA);
            load_col64(P1w, lane, WB);
            load_col64(S1w, lane, WC);
            pin64(WA); pin64(WB); pin64(WC);
            {
                float s = bmv_s(agg1 + na*64, WA);
                float scp = bmv_s(nf1b + na*64, WC);
                float gate = p0 + p1*s + p2*s*s;
                sA = s;
                nfA = bmv_lds(s*gate, WB, slice, lane) + scp*asc1[spa*64+lane];
            }
            if (vb){
                float s = bmv_s(agg1 + nb*64, WA);
                float scp = bmv_s(nf1b + nb*64, WC);
                float gate = p0 + p1*s + p2*s*s;
                sB = s;
                nfB = bmv_lds(s*gate, WB, slice, lane) + scp*asc1[spb*64+lane];
            }
        }
        {   // phase b: readout fwd + bwd
            int j = lane & 15;
            float w2 = w_r2[j];
            float Wcol[64];
#pragma unroll
            for (int c=0;c<64;c++) Wcol[c] = W_r1[c*16 + j];
            pin64(Wcol);
            float Wrow[16];
#pragma unroll
            for (int i2=0;i2<4;i2++){
                float4 v = reinterpret_cast<const float4*>(W_r1 + lane*16)[i2];
                Wrow[4*i2]=v.x; Wrow[4*i2+1]=v.y; Wrow[4*i2+2]=v.z; Wrow[4*i2+3]=v.w;
            }
            {
                float z  = bmv_lds(nfA, Wcol, slice, lane);
                float ne = siluf(z)*w2;
#pragma unroll
                for (int off=32;off;off>>=1) ne += __shfl_xor(ne,off);
                ne *= 0.25f;
                float gz = w2*dsiluf(z);
                slice[lane] = gz;
                float g = 0.f;
#pragma unroll
                for (int jj=0;jj<16;jj+=4){
                    float4 a = *reinterpret_cast<const float4*>(slice + jj);
                    g += a.x*Wrow[jj] + a.y*Wrow[jj+1] + a.z*Wrow[jj+2] + a.w*Wrow[jj+3];
                }
                gA = g;
                if (lane==0){ out[8+na] += ne; atomicAdd(&part[batch[na]], ne); }
            }
            if (vb){
                float z  = bmv_lds(nfB, Wcol, slice, lane);
                float ne = siluf(z)*w2;
#pragma unroll
                for (int off=32;off;off>>=1) ne += __shfl_xor(ne,off);
                ne *= 0.25f;
                float gz = w2*dsiluf(z);
                slice[lane] = gz;
                float g = 0.f;
#pragma unroll
                for (int jj=0;jj<16;jj+=4){
                    float4 a = *reinterpret_cast<const float4*>(slice + jj);
                    g += a.x*Wrow[jj] + a.y*Wrow[jj+1] + a.z*Wrow[jj+2] + a.w*Wrow[jj+3];
                }
                gB = g;
                if (lane==0){ out[8+nb] += ne; atomicAdd(&part[batch[nb]], ne); }
            }
        }
        {   // phase c: node bwd (row-form)
            float WA[64], WB[64], WC[64];
            load_row64(P1w + lane*64, WA);
            load_row64(O1  + lane*64, WB);
            load_row64(S1w + lane*64, WC);
            pin64(WA); pin64(WB); pin64(WC);
            {
                float gv = bmv_lds(gA, WA, slice, lane);
                float gate = p0 + p1*sA + p2*sA*sA;
                float gs = gv*(gate + sA*(p1 + 2.0f*p2*sA));
                gagg1[na*64+lane] = bmv_lds(gs, WB, slice, lane);
                gacc [na*64+lane] = bmv_lds(gA*asc1[spa*64+lane], WC, slice, lane);
            }
            if (vb){
                float gv = bmv_lds(gB, WA, slice, lane);
                float gate = p0 + p1*sB + p2*sB*sB;
                float gs = gv*(gate + sB*(p1 + 2.0f*p2*sB));
                gagg1[nb*64+lane] = bmv_lds(gs, WB, slice, lane);
                gacc [nb*64+lane] = bmv_lds(gB*asc1[spb*64+lane], WC, slice, lane);
            }
        }
        __syncthreads();
        if (tid < 8) atomicAdd(&out[tid], part[tid]);
    }
    gbar(barcnt, 4);

    // ================= P6: edge bwd layer1 (ghb + forces) =================
    {
        int cnt = ecount[0];
        float W3r[64], W2r[64], W1c[8];
        load_row64(W3z1 + lane*64, W3r);
        load_row64(M2_1 + lane*64, W2r);
#pragma unroll
        for (int j=0;j<8;j++) W1c[j] = M1_1[j*64+lane];
        pin64(W3r); pin64(W2r); pin8(W1c);
        for (int slot=gw; slot<cnt; slot+=NWAVE){
            int us = rfl(slot);
            int s = esrc[us], r = edst[us];
            float gm = gagg1[r*64+lane]*INV_AVG;
            float h  = h1b[s*64+lane];
            atomicAdd(&ghb[s*64+lane], gm*w0b1[(size_t)us*64+lane]);
            float ga2 = bmv_lds(gm*h, W3r, slice, lane);
            float gt2 = ga2*dsiluf(t2b1[(size_t)us*64+lane]);
            float ga1 = bmv_lds(gt2, W2r, slice, lane);
            const float* fn  = frc  + us*8;
            const float* dfn = dfrc + us*8;
            float t1=0.f, wd=0.f;
#pragma unroll
            for (int j=0;j<8;j++){ t1 += fn[j]*W1c[j]; wd += dfn[j]*W1c[j]; }
            float p = ga1*dsiluf(t1)*wd;
#pragma unroll
            for (int off=32;off;off>>=1) p += __shfl_xor(p,off);
            if (lane<3) atomicAdd(&outf[r*3+lane], -u3c[us*3+lane]*p);
            else if (lane>=32 && lane<35){ int d=lane-32; atomicAdd(&outf[s*3+d], u3c[us*3+d]*p); }
        }
    }
    gbar(barcnt, 5);

    // ================= P7: assemble gnf1 + node bwd layer0 -> gagg0 =================
    {
        float WA[64], WB[64], WC[64];
        load_row64(U1  + lane*64, WA);
        load_row64(P0w + lane*64, WB);
        load_row64(O0  + lane*64, WC);
        pin64(WA); pin64(WB); pin64(WC);
        float p0=pl0[lane], p1=pl0[64+lane], p2=pl0[128+lane];
        float w0r = w_r0[lane];
        for (int n=gw; n<NN; n+=NWAVE){
            const float* ghn = ghb + n*64;          // uniform
            float g  = bmv_s(ghn, WA) + gacc[n*64+lane] + w0r;
            float gv = bmv_lds(g, WB, slice, lane);
            float s  = s0b[n*64+lane];
            float gate = p0 + p1*s + p2*s*s;
            float gs = gv*(gate + s*(p1 + 2.0f*p2*s));
            gagg0[n*64+lane] = bmv_lds(gs, WC, slice, lane);
        }
    }
    gbar(barcnt, 6);

    // ================= P8: edge bwd layer0 (forces) =================
    {
        int cnt = ecount[0];
        float W3r[64], W2r[64], W1c[8];
        load_row64(W3z0 + lane*64, W3r);
        load_row64(M2_0 + lane*64, W2r);
#pragma unroll
        for (int j=0;j<8;j++) W1c[j] = M1_0[j*64+lane];
        pin64(W3r); pin64(W2r); pin8(W1c);
        for (int slot=gw; slot<cnt; slot+=NWAVE){
            int us = rfl(slot);
            int s = esrc[us], r = edst[us];
            float gm = gagg0[r*64+lane]*INV_AVG;
            float h  = T0[spec[s]*64+lane];
            float ga2 = bmv_lds(gm*h, W3r, slice, lane);
            float gt2 = ga2*dsiluf(t2b0[(size_t)us*64+lane]);
            float ga1 = bmv_lds(gt2, W2r, slice, lane);
            const float* fn  = frc  + us*8;
            const float* dfn = dfrc + us*8;
            float t1=0.f, wd=0.f;
#pragma unroll
            for (int j=0;j<8;j++){ t1 += fn[j]*W1c[j]; wd += dfn[j]*W1c[j]; }
            float p = ga1*dsiluf(t1)*wd;
#pragma unroll
            for (int off=32;off;off>>=1) p += __shfl_xor(p,off);
            if (lane<3) atomicAdd(&outf[r*3+lane], -u3c[us*3+lane]*p);
            else if (lane>=32 && lane<35){ int d=lane-32; atomicAdd(&outf[s*3+d], u3c[us*3+d]*p); }
        }
    }
}

extern "C" void kernel_launch(void* const* d_in, const int* in_sizes, int n_in,
                              void* d_out, int out_size, void* d_ws, size_t ws_size,
                              hipStream_t stream)
{
    (void)in_sizes; (void)n_in; (void)out_size; (void)ws_size;
    const float* pos    = (const float*)d_in[0];
    const float* x      = (const float*)d_in[1];
    const float* shifts = (const float*)d_in[2];
    const float* W_embed= (const float*)d_in[3];
    const float* W_up   = (const float*)d_in[4];
    const float* Wm1    = (const float*)d_in[5];
    const float* Wm2    = (const float*)d_in[6];
    const float* Wm3    = (const float*)d_in[7];
    const float* W_out  = (const float*)d_in[8];
    const float* W_sc   = (const float*)d_in[9];
    const float* a_sc   = (const float*)d_in[10];
    const float* w_poly = (const float*)d_in[11];
    const float* W_prod = (const float*)d_in[12];
    const float* w_r0   = (const float*)d_in[13];
    const float* W_r1   = (const float*)d_in[14];
    const float* w_r2   = (const float*)d_in[15];
    const int*   ei     = (const int*)d_in[16];
    const int*   batch  = (const int*)d_in[17];
    float* out = (float*)d_out;

    float* F = (float*)d_ws;
    float* agg0 = F; F += NN*64;          // zws zero region: agg0,agg1,ghb
    float* agg1 = F; F += NN*64;
    float* ghb  = F; F += NN*64;
    float* u3c  = F; F += 3*EE;
    float* frc  = F; F += 8*EE;
    float* dfrc = F; F += 8*EE;
    float* t2b0 = F; F += (size_t)EE*64;
    float* t2b1 = F; F += (size_t)EE*64;
    float* w0b1 = F; F += (size_t)EE*64;
    float* h1b  = F; F += NN*64;
    float* nf1b = F; F += NN*64;
    float* s0b  = F; F += NN*64;
    float* gagg1= F; F += NN*64;
    float* gagg0= F; F += NN*64;
    float* gacc = F; F += NN*64;
    float* T0   = F; F += ZZ*64;
    float* SC0  = F; F += ZZ*64;
    float* W3z  = F; F += 2*64*64;
    int* spec   = (int*)F; F += NN;
    int* esrc   = (int*)F; F += EE;
    int* edst   = (int*)F; F += EE;
    int* ecount = (int*)F; F += 4;
    int* barcnt = (int*)F; F += 512;

    k_zero<<<1, 256, 0, stream>>>(barcnt, ecount, out);
    k_main<<<GRID, 256, 0, stream>>>(pos, shifts, ei, x, W_embed, W_up, Wm1, Wm2, Wm3,
                                     W_out, W_sc, a_sc, w_poly, W_prod, w_r0, W_r1, w_r2,
                                     batch, spec, u3c, frc, dfrc, esrc, edst, ecount,
                                     T0, SC0, W3z, agg0, agg1, ghb, t2b0, t2b1, w0b1,
                                     h1b, nf1b, s0b, gagg0, gagg1, gacc,
                                     barcnt, (float4*)d_ws, out);
}